// Round 1
// baseline (268.593 us; speedup 1.0000x reference)
//
#include <hip/hip_runtime.h>

typedef _Float16 f16;
typedef _Float16 f16x8 __attribute__((ext_vector_type(8)));
typedef float f32x4 __attribute__((ext_vector_type(4)));
typedef unsigned short u16;

#define NATOMS 65536
#define SLOT 5120   // f16 elems per buffer: 10 frags x 512
#define NBUF 2      // double-buffered weight stream

// ---------------- workspace layout ----------------
#define WS_LISTS_OFF 256
#define WS_W_OFF 524544
#define WS_W_ELEMS 350208
#define WS_NEEDED (WS_W_OFF + WS_W_ELEMS * 2)

struct ConvJob { const float* src; int K, N, KS, NT, CK, off; };

struct PrepParams {
  const int* species;
  int* counts;
  u16* lists;
  f16* wbase;
  ConvJob jobs[16];
};

struct MlpParams {
  const float* aev;
  const float* b0;
  const float* b1;
  const float* bias[4][4];
  const f16* w[4][4];       // fragment-packed, chunk-major (CK=1: frag = ks*NT + nt)
  const int* counts;
  const u16* lists;
  float* out;
  int Nreal0[4];            // {160,144,128,128}
  int Nreal1[4];            // {128,112,112,112}
};

// A-fragment / accumulator bundles passed BY VALUE so SROA keeps them in VGPRs
// (pointer-passing escaped the array and forced scratch reloads - prior-session bug).
template <int N> struct AF { f16x8 v[N]; };
template <int N> struct ACC { f32x4 v[N]; };

// ---------------- prep: routing (blocks 0..255) + weight pack (blocks 256..735) ----
__global__ __launch_bounds__(256) void prep_kernel(PrepParams p) {
  int tid = threadIdx.x;
  if (blockIdx.x < 256) {
    __shared__ int wcnt[4][4];
    __shared__ int wbase[4][4];
    int i = blockIdx.x * 256 + tid;
    int s = p.species[i];
    int wave = tid >> 6, lane = tid & 63;
    unsigned long long m[4];
    #pragma unroll
    for (int t = 0; t < 4; t++) {
      m[t] = __ballot(s == t);
      if (lane == 0) wcnt[wave][t] = __popcll(m[t]);
    }
    __syncthreads();
    if (tid < 4) {
      int t = tid;
      int c0 = wcnt[0][t], c1 = wcnt[1][t], c2 = wcnt[2][t], c3 = wcnt[3][t];
      int base = atomicAdd(&p.counts[t], c0 + c1 + c2 + c3);
      wbase[0][t] = base;
      wbase[1][t] = base + c0;
      wbase[2][t] = base + c0 + c1;
      wbase[3][t] = base + c0 + c1 + c2;
    }
    __syncthreads();
    int rnk = __popcll(m[s] & ((1ull << lane) - 1ull));
    p.lists[s * NATOMS + wbase[wave][s] + rnk] = (u16)i;
  } else {
    // pack fp32 [K][N] -> fp16 fragments, chunk-major consumption order
    int bx = blockIdx.x - 256;
    int job = bx / 30, bxin = bx - job * 30;
    ConvJob jb = p.jobs[job];
    int e = bxin * 256 + tid;
    int nslots = jb.KS * jb.NT * 64;
    if (e >= nslots) return;
    int frag = e >> 6, lane = e & 63;
    int c = frag / (jb.CK * jb.NT);
    int rem = frag - c * (jb.CK * jb.NT);
    int ckc = min(jb.CK, jb.KS - c * jb.CK);
    int nt = rem / ckc, ki = rem - nt * ckc;
    int ks = c * jb.CK + ki;
    int q = lane >> 4, nlo = lane & 15;
    int n = nt * 16 + nlo;
    int k0 = ks * 32 + q * 8;
    f16x8 v;
    #pragma unroll
    for (int j = 0; j < 8; j++) {
      int k = k0 + j;
      float x = (n < jb.N && k < jb.K) ? jb.src[k * jb.N + n] : 0.f;
      v[j] = (f16)x;
    }
    *(f16x8*)(p.wbase + jb.off + (size_t)e * 8) = v;
  }
}

__device__ __forceinline__ float celu01(float v) {
  return v > 0.f ? v : 0.1f * (__expf(v * 10.f) - 1.f);
}

// stage one 1KB fragment (64 lanes x 16B) global -> LDS
__device__ __forceinline__ void stage_frag(const f16* g, f16* l, int lane) {
  __builtin_amdgcn_global_load_lds(
      (const __attribute__((address_space(1))) unsigned int*)(g + lane * 8),
      (__attribute__((address_space(3))) unsigned int*)l, 16, 0, 0);
}

// ---------------- compile-time chunk schedule ----------------
// L0: 12 chunks x NT0 frags; L1: KS1 x 8; L2: 4 x 6; L3: 1 x 3
template <int NT0, int KS1>
struct Sched {
  static constexpr int NC = 12 + KS1 + 4 + 1;
  static constexpr int frags(int c) {
    return c < 12 ? NT0 : (c < 12 + KS1 ? 8 : (c < 12 + KS1 + 4 ? 6 : 3));
  }
};

// stage chunk C cooperatively: wave w takes frag w (and w+8 when NF>8).
// Branches are wave-uniform (w uniform per wave), so global_load_lds stays legal.
template <int NT0, int KS1, int C>
__device__ __forceinline__ void stage_chunk(const f16* w0, const f16* w1,
                                            const f16* w2, const f16* w3,
                                            f16* ring, int w, int lane) {
  constexpr int NF = Sched<NT0, KS1>::frags(C);
  const f16* g;
  if constexpr (C < 12) g = w0 + (size_t)C * NT0 * 512;
  else if constexpr (C < 12 + KS1) g = w1 + (size_t)(C - 12) * 8 * 512;
  else if constexpr (C < 12 + KS1 + 4) g = w2 + (size_t)(C - 12 - KS1) * 6 * 512;
  else g = w3;
  f16* l = ring + (C % NBUF) * SLOT;
  if (w < NF) stage_frag(g + w * 512, l + w * 512, lane);
  if constexpr (NF > 8) {
    if (w + 8 < NF) stage_frag(g + (w + 8) * 512, l + (w + 8) * 512, lane);
  }
}

// one K-chunk step: issue stage of chunk G+1 (other buffer), MFMA chunk G,
// then __syncthreads (vmcnt(0)+barrier) makes G+1 ready for the next step.
// Ring safety: stage(G+1) overwrites chunk G-1's buffer; all waves finished
// reading G-1 at the barrier that ended the previous step.
template <int NT0, int KS1, int CB, int KS, int NT, int I>
__device__ __forceinline__ ACC<NT> layer_step(AF<KS> a, ACC<NT> acc, f16* ring,
    const f16* s0, const f16* s1, const f16* s2, const f16* s3, int w, int lane) {
  if constexpr (I == KS) {
    return acc;
  } else {
    constexpr int G = CB + I;
    if constexpr (G + 1 < Sched<NT0, KS1>::NC)
      stage_chunk<NT0, KS1, G + 1>(s0, s1, s2, s3, ring, w, lane);
    const f16* slot = ring + (G % NBUF) * SLOT;
    #pragma unroll
    for (int nt = 0; nt < NT; nt++) {
      f16x8 b = *(const f16x8*)(slot + nt * 512 + lane * 8);
      acc.v[nt] = __builtin_amdgcn_mfma_f32_16x16x32_f16(a.v[I], b, acc.v[nt], 0, 0, 0);
    }
    __syncthreads();
    return layer_step<NT0, KS1, CB, KS, NT, I + 1>(a, acc, ring, s0, s1, s2, s3, w, lane);
  }
}

template <int NT0, int KS1, int CB, int KS, int NT, bool ACT>
__device__ __forceinline__ void consume_layer(AF<KS> a, f16* ring,
    const f16* s0, const f16* s1, const f16* s2, const f16* s3,
    const float* __restrict__ bias, int Nreal, f16* dstw, int w, int lane,
    int q, int nlo) {
  ACC<NT> acc;
  #pragma unroll
  for (int nt = 0; nt < NT; nt++) acc.v[nt] = f32x4{0.f, 0.f, 0.f, 0.f};
  acc = layer_step<NT0, KS1, CB, KS, NT, 0>(a, acc, ring, s0, s1, s2, s3, w, lane);
  // epilogue: bias + CELU, write wave-private Bf rows (wave-local; no barrier needed,
  // lgkmcnt ordering covers the ds_write -> ds_read handoff to the next layer)
  #pragma unroll
  for (int nt = 0; nt < NT; nt++) {
    int n = nt * 16 + nlo;
    float bv = (n < Nreal) ? bias[n] : 0.f;
    #pragma unroll
    for (int r = 0; r < 4; r++) {
      float v = acc.v[nt][r] + bv;
      if (ACT) v = celu01(v);
      dstw[(q * 4 + r) * 168 + n] = (f16)v;
    }
  }
}

// ---------------- fused routed MLP: 8 compute waves x 16 atoms = 128 atoms/block ----
// No producer wave, no flag/done machinery: all waves cooperatively stage the next
// weight chunk (global_load_lds) before computing the current one; __syncthreads
// per chunk both drains the DMA (vmcnt0) and recycles the double buffer.
template <int NT0, int KS1>
__device__ __forceinline__ void mlp_body(const MlpParams& p, int s, int tile,
                                         f16* ring, f16* Bf) {
  int cnt = p.counts[s];
  if (tile * 128 >= cnt) return;   // uniform early-exit, before any barrier
  int tid = threadIdx.x, w = tid >> 6, lane = tid & 63;
  const f16 *s0 = p.w[s][0], *s1 = p.w[s][1], *s2 = p.w[s][2], *s3 = p.w[s][3];

  // kick off chunk 0 DMA first so it overlaps the aev loads below
  stage_chunk<NT0, KS1, 0>(s0, s1, s2, s3, ring, w, lane);

  const u16* list = p.lists + s * NATOMS;
  int q = lane >> 4, nlo = lane & 15;
  int rowbase = tile * 128 + w * 16;
  int atom = list[min(rowbase + nlo, cnt - 1)];

  // layer-0 A: direct global fp32 -> fp16 fragments, held in VGPRs
  AF<12> a0;
  const float* ap = p.aev + (size_t)atom * 384 + q * 8;
  #pragma unroll
  for (int ks = 0; ks < 12; ks++) {
    float4 u0 = *(const float4*)(ap + ks * 32);
    float4 u1 = *(const float4*)(ap + ks * 32 + 4);
    f16x8 t = {(f16)u0.x, (f16)u0.y, (f16)u0.z, (f16)u0.w,
               (f16)u1.x, (f16)u1.y, (f16)u1.z, (f16)u1.w};
    a0.v[ks] = t;
  }
  __syncthreads();  // chunk 0 staged by all waves

  f16* my = Bf + (w * 16) * 168;  // wave-private rows, reused by all layers

  consume_layer<NT0, KS1, 0, 12, NT0, true>(a0, ring, s0, s1, s2, s3,
      p.bias[s][0], p.Nreal0[s], my, w, lane, q, nlo);
  AF<KS1> a1;
  #pragma unroll
  for (int ks = 0; ks < KS1; ks++)
    a1.v[ks] = *(const f16x8*)(my + nlo * 168 + ks * 32 + q * 8);
  consume_layer<NT0, KS1, 12, KS1, 8, true>(a1, ring, s0, s1, s2, s3,
      p.bias[s][1], p.Nreal1[s], my, w, lane, q, nlo);
  AF<4> a2;
  #pragma unroll
  for (int ks = 0; ks < 4; ks++)
    a2.v[ks] = *(const f16x8*)(my + nlo * 168 + ks * 32 + q * 8);
  consume_layer<NT0, KS1, 12 + KS1, 4, 6, true>(a2, ring, s0, s1, s2, s3,
      p.bias[s][2], 96, my, w, lane, q, nlo);

  // layer 3: single chunk (3 frags), K=96, N=1 — staged during layer 2's last step
  AF<3> a3;
  #pragma unroll
  for (int ks = 0; ks < 3; ks++)
    a3.v[ks] = *(const f16x8*)(my + nlo * 168 + ks * 32 + q * 8);
  constexpr int G3 = 12 + KS1 + 4;
  const f16* slot = ring + (G3 % NBUF) * SLOT;
  f32x4 acc3 = {0.f, 0.f, 0.f, 0.f};
  #pragma unroll
  for (int ks = 0; ks < 3; ks++) {
    f16x8 b = *(const f16x8*)(slot + ks * 512 + lane * 8);
    acc3 = __builtin_amdgcn_mfma_f32_16x16x32_f16(a3.v[ks], b, acc3, 0, 0, 0);
  }
  if (nlo == 0) {
    float b3 = p.bias[s][3][0];
    float b0v = p.b0[s], b1v = p.b1[s];
    #pragma unroll
    for (int r = 0; r < 4; r++) {
      int m = rowbase + q * 4 + r;
      if (m < cnt) {
        float coef = acc3[r] + b3;
        p.out[list[m]] = b0v + b1v * coef;
      }
    }
  }
}

// LDS: ring 2*10240=20480B + Bf 128*168*2=43008B = 63488B -> 2 blocks/CU (16 waves/CU)
// launch_bounds(512,4): 4 waves/EU -> VGPR cap 128 (A-frags 48 + acc 40 + B-frags +
// addr fits without scratch spills; prior kernel's cap-64 allocation spilled ~8MB)
__global__ __launch_bounds__(512, 4) void mlp_kernel(MlpParams p) {
  __shared__ __align__(16) f16 ring[NBUF * SLOT];
  __shared__ __align__(16) f16 Bf[128 * 168];
  int s = blockIdx.x & 3;
  int tile = blockIdx.x >> 2;
  switch (s) {
    case 0: mlp_body<10, 5>(p, 0, tile, ring, Bf); break;  // H 384->160->128->96->1
    case 1: mlp_body<10, 5>(p, 1, tile, ring, Bf); break;  // C (144 pad 160)
    case 2: mlp_body<8, 4>(p, 2, tile, ring, Bf); break;   // N 384->128->112->96->1
    default: mlp_body<8, 4>(p, 3, tile, ring, Bf); break;  // O
  }
}

extern "C" void kernel_launch(void* const* d_in, const int* in_sizes, int n_in,
                              void* d_out, int out_size, void* d_ws, size_t ws_size,
                              hipStream_t stream) {
  if (ws_size < WS_NEEDED) return;  // workspace too small — fail loud

  const int* species = (const int*)d_in[0];
  const float* aev = (const float*)d_in[1];
  const float* b0 = (const float*)d_in[2];
  const float* b1 = (const float*)d_in[3];

  static const int F1[4]  = {160, 144, 128, 128};
  static const int F1p[4] = {160, 160, 128, 128};
  static const int F2[4]  = {128, 112, 112, 112};

  char* wsb = (char*)d_ws;
  int* counts = (int*)wsb;
  u16* lists = (u16*)(wsb + WS_LISTS_OFF);
  f16* wbase = (f16*)(wsb + WS_W_OFF);

  PrepParams pp;
  pp.species = species; pp.counts = counts; pp.lists = lists; pp.wbase = wbase;

  MlpParams mp;
  mp.aev = aev; mp.b0 = b0; mp.b1 = b1;
  mp.counts = counts; mp.lists = lists; mp.out = (float*)d_out;

  int off = 0, ji = 0;
  for (int s = 0; s < 4; s++) {
    int K[4]  = {384, F1[s], F2[s], 96};
    int N[4]  = {F1[s], F2[s], 96, 1};
    int KS[4] = {12, F1p[s] / 32, 4, 3};
    int NT[4] = {F1p[s] / 16, 8, 6, 1};
    int CK[4] = {1, 1, 1, 3};
    for (int l = 0; l < 4; l++) {
      const float* w = (const float*)d_in[4 + s * 8 + l * 2];
      const float* b = (const float*)d_in[4 + s * 8 + l * 2 + 1];
      pp.jobs[ji].src = w;
      pp.jobs[ji].K = K[l];
      pp.jobs[ji].N = N[l];
      pp.jobs[ji].KS = KS[l];
      pp.jobs[ji].NT = NT[l];
      pp.jobs[ji].CK = CK[l];
      pp.jobs[ji].off = off;
      mp.w[s][l] = wbase + off;
      mp.bias[s][l] = b;
      off += KS[l] * NT[l] * 512;
      ji++;
    }
    mp.Nreal0[s] = F1[s];
    mp.Nreal1[s] = F2[s];
  }

  hipMemsetAsync(d_ws, 0, 64, stream);
  prep_kernel<<<dim3(256 + 480), 256, 0, stream>>>(pp);
  // 140 tiles/species x 128 atoms = 17920 capacity (~+13 sigma vs expected 16384)
  mlp_kernel<<<dim3(140 * 4), 512, 0, stream>>>(mp);
}